// Round 2
// baseline (241.079 us; speedup 1.0000x reference)
//
#include <hip/hip_runtime.h>
#include <hip/hip_bf16.h>

// ---- problem constants ----
#define T_TOK 2048
#define HID   1024
#define FF    1024
#define NEXP  8
#define NPAIR 4096

// ---- GEMM tiling ----
#define BM 128
#define BK 32
#define MAX_MT 40
#define MAXROWS (MAX_MT*BM)   // 5120

using bf16x8 = __attribute__((ext_vector_type(8))) __bf16;
using f32x4  = __attribute__((ext_vector_type(4))) float;

__device__ __forceinline__ unsigned short f2bf(float f) {
    unsigned int u = __float_as_uint(f);
    unsigned int r = (u + 0x7FFF + ((u >> 16) & 1)) >> 16;   // RNE
    return (unsigned short)r;
}
__device__ __forceinline__ float bf2f(unsigned short s) {
    return __uint_as_float(((unsigned int)s) << 16);
}

// ---------------- setup: bucket pairs by expert, build row maps ----------------
__global__ void setup_kernel(const int* __restrict__ ids,
                             const float* __restrict__ tw,
                             int* __restrict__ pair_pos,
                             int* __restrict__ row_tok,
                             float* __restrict__ row_w,
                             int* __restrict__ meta) {
    __shared__ int cnt[NEXP], cnt2[NEXP], base[NEXP];
    int tid = threadIdx.x;
    if (tid < NEXP) { cnt[tid] = 0; cnt2[tid] = 0; }
    __syncthreads();
    for (int p = tid; p < NPAIR; p += 256) atomicAdd(&cnt[ids[p]], 1);
    for (int i = tid; i < MAXROWS; i += 256) row_tok[i] = -1;
    __syncthreads();
    if (tid == 0) {
        int mt = 0;
        for (int e = 0; e < NEXP; e++) {
            meta[e] = mt;
            base[e] = mt * BM;
            mt += (cnt[e] + BM - 1) / BM;
        }
        meta[NEXP] = mt;
    }
    __syncthreads();
    for (int p = tid; p < NPAIR; p += 256) {
        int e = ids[p];
        int pos = base[e] + atomicAdd(&cnt2[e], 1);
        pair_pos[p] = pos;
        row_tok[pos] = p >> 1;
        row_w[pos] = tw[p];
    }
}

// ---------------- prep: cvt wgu (interleaved gate/up rows) + cvt wdn + gather A ----
// one block per 1024-element row; 256 threads x 4 elems.
#define NB_GU (NEXP*2*FF)            // 16384
#define NB_DN (NEXP*HID)             // 8192
__global__ void prep_kernel(const float* __restrict__ wgu,
                            const float* __restrict__ wdn,
                            const float* __restrict__ hs,
                            const int* __restrict__ pair_pos,
                            unsigned short* __restrict__ wgu_b,
                            unsigned short* __restrict__ wdn_b,
                            unsigned short* __restrict__ A) {
    int b = blockIdx.x;
    int c = threadIdx.x * 4;
    const float* src;
    unsigned short* dst;
    if (b < NB_GU) {
        int e = b >> 11;             // / (2*FF)
        int o = b & (2 * FF - 1);
        int nr = (o < FF) ? (2 * o) : (2 * (o - FF) + 1);   // interleave gate/up
        src = wgu + (long)b * HID;
        dst = wgu_b + ((long)e * 2 * FF + nr) * HID;
    } else if (b < NB_GU + NB_DN) {
        int rb = b - NB_GU;
        src = wdn + (long)rb * FF;
        dst = wdn_b + (long)rb * FF;
    } else {
        int p = b - (NB_GU + NB_DN);
        int t = p >> 1;
        src = hs + (long)t * HID;
        dst = A + (long)pair_pos[p] * HID;
    }
    float4 v = *(const float4*)(src + c);
    ushort4 o;
    o.x = f2bf(v.x); o.y = f2bf(v.y); o.z = f2bf(v.z); o.w = f2bf(v.w);
    *(ushort4*)(dst + c) = o;
}

// ---------------- grouped GEMM, templated epilogue ----------------
// EPI==1: silu(gate)*up via lane-pair shuffle (B rows interleaved), bf16 out (cols Ntot/2)
// EPI==2: weighted atomic scatter-combine into fp32 out via row_tok/row_w
template<int BN_, int EPI>
__global__ __launch_bounds__(256)
void gemm_moe(const unsigned short* __restrict__ A,
              const unsigned short* __restrict__ B,
              unsigned short* __restrict__ Cbf,
              float* __restrict__ outf,
              const int* __restrict__ meta,
              const int* __restrict__ row_tok,
              const float* __restrict__ row_w,
              int K, int Ntot, long Bexp) {
    __shared__ unsigned short As[BM * BK];
    __shared__ unsigned short Bs[BN_ * BK];
    int bx = blockIdx.x, by = blockIdx.y;
    if (bx >= meta[NEXP]) return;
    int e = 0;
#pragma unroll
    for (int i = 1; i < NEXP; i++) if (bx >= meta[i]) e = i;

    long m0 = (long)bx * BM;
    long n0 = (long)by * BN_;
    const unsigned short* Ab = A + m0 * K;
    const unsigned short* Bb = B + (long)e * Bexp + n0 * K;

    int tid = threadIdx.x, lane = tid & 63, wv = tid >> 6;
    const int qr8 = (lane >> 4) * 8;
    const int r = lane & 15;
    const int quad = lane >> 4;
    const int mw = (wv >> 1) * 64, nw = (wv & 1) * (BN_ / 2);
    constexpr int NJ = BN_ / 32;

    f32x4 acc[4][NJ] = {};

    for (int k0 = 0; k0 < K; k0 += BK) {
        __syncthreads();
#pragma unroll
        for (int it = 0; it < 2 + BN_ / 64; it++) {
            int chunk = it * 256 + tid;
            const unsigned short* g;
            unsigned short* l;
            if (it < 2) {                       // A chunks 0..511
                int row = chunk >> 2, cc = chunk & 3;
                g = Ab + (long)row * K + k0 + cc * 8;
                l = &As[chunk * 8];
            } else {                            // B chunks
                int cb = chunk - 512;
                int row = cb >> 2, cc = cb & 3;
                g = Bb + (long)row * K + k0 + cc * 8;
                l = &Bs[cb * 8];
            }
            __builtin_amdgcn_global_load_lds(
                (const __attribute__((address_space(1))) void*)(const void*)g,
                (__attribute__((address_space(3))) void*)(void*)l, 16, 0, 0);
        }
        __syncthreads();

        bf16x8 a[4], b[NJ];
#pragma unroll
        for (int i = 0; i < 4; i++)
            a[i] = *(const bf16x8*)&As[(mw + i * 16 + r) * BK + qr8];
#pragma unroll
        for (int j = 0; j < NJ; j++)
            b[j] = *(const bf16x8*)&Bs[(nw + j * 16 + r) * BK + qr8];
#pragma unroll
        for (int i = 0; i < 4; i++)
#pragma unroll
            for (int j = 0; j < NJ; j++)
                acc[i][j] = __builtin_amdgcn_mfma_f32_16x16x32_bf16(a[i], b[j], acc[i][j], 0, 0, 0);
    }

    // D layout: row = quad*4 + reg, col = lane&15 within each 16x16 tile
    if (EPI == 1) {
#pragma unroll
        for (int i = 0; i < 4; i++) {
            long rowb = m0 + mw + i * 16 + quad * 4;
#pragma unroll
            for (int j = 0; j < NJ; j++) {
                int n = (int)n0 + nw + j * 16 + r;
#pragma unroll
                for (int reg = 0; reg < 4; reg++) {
                    float v = acc[i][j][reg];
                    float o = __shfl_xor(v, 1);      // partner col (all lanes execute)
                    if (!(r & 1)) {
                        float g = v, u = o;
                        float s = g / (1.f + __expf(-g)) * u;
                        Cbf[(rowb + reg) * (long)(Ntot / 2) + (n >> 1)] = f2bf(s);
                    }
                }
            }
        }
    } else {
#pragma unroll
        for (int i = 0; i < 4; i++) {
            int rowb = (int)m0 + mw + i * 16 + quad * 4;
            int tk[4]; float w[4];
#pragma unroll
            for (int reg = 0; reg < 4; reg++) {
                tk[reg] = row_tok[rowb + reg];
                w[reg] = row_w[rowb + reg];
            }
#pragma unroll
            for (int j = 0; j < NJ; j++) {
                int n = (int)n0 + nw + j * 16 + r;
#pragma unroll
                for (int reg = 0; reg < 4; reg++) {
                    if (tk[reg] >= 0)
                        atomicAdd(outf + (long)tk[reg] * HID + n, w[reg] * acc[i][j][reg]);
                }
            }
        }
    }
}

extern "C" void kernel_launch(void* const* d_in, const int* in_sizes, int n_in,
                              void* d_out, int out_size, void* d_ws, size_t ws_size,
                              hipStream_t stream) {
    const float* hs  = (const float*)d_in[0];
    const float* tw  = (const float*)d_in[1];
    const int*   ids = (const int*)d_in[2];
    const float* wgu = (const float*)d_in[3];
    const float* wdn = (const float*)d_in[4];
    float* out = (float*)d_out;

    char* ws = (char*)d_ws;
    size_t off = 0;
    auto alloc = [&](size_t bytes) -> void* {
        void* p = ws + off;
        off += (bytes + 255) & ~(size_t)255;
        return p;
    };
    unsigned short* wgu_b = (unsigned short*)alloc((size_t)NEXP * 2 * FF * HID * 2); // 32 MB
    unsigned short* wdn_b = (unsigned short*)alloc((size_t)NEXP * HID * FF * 2);     // 16 MB
    unsigned short* Abuf  = (unsigned short*)alloc((size_t)MAXROWS * HID * 2);       // 10 MB
    unsigned short* act   = (unsigned short*)alloc((size_t)MAXROWS * FF * 2);        // 10 MB
    int*   pair_pos = (int*)alloc(NPAIR * 4);
    int*   row_tok  = (int*)alloc(MAXROWS * 4);
    float* row_w    = (float*)alloc(MAXROWS * 4);
    int*   meta     = (int*)alloc(64);

    // pad rows of A must be zero (partial M-tiles); out accumulated via atomics
    hipMemsetAsync(Abuf, 0, (size_t)MAXROWS * HID * 2, stream);
    hipMemsetAsync(out, 0, (size_t)T_TOK * HID * 4, stream);

    setup_kernel<<<1, 256, 0, stream>>>(ids, tw, pair_pos, row_tok, row_w, meta);
    prep_kernel<<<NB_GU + NB_DN + NPAIR, 256, 0, stream>>>(
        wgu, wdn, hs, pair_pos, wgu_b, wdn_b, Abuf);

    // GEMM1: (rows x 1024) x (2048 x 1024)^T -> fused silu -> act (rows x 1024)
    gemm_moe<64, 1><<<dim3(MAX_MT, (2 * FF) / 64), 256, 0, stream>>>(
        Abuf, wgu_b, act, nullptr, meta, nullptr, nullptr,
        HID, 2 * FF, (long)(2 * FF) * HID);

    // GEMM2: (rows x 1024) x (1024 x 1024)^T -> weighted atomic combine -> out
    gemm_moe<64, 2><<<dim3(MAX_MT, HID / 64), 256, 0, stream>>>(
        act, wdn_b, nullptr, out, meta, row_tok, row_w,
        FF, HID, (long)HID * FF);
}

// Round 3
// 237.134 us; speedup vs baseline: 1.0166x; 1.0166x over previous
//
#include <hip/hip_runtime.h>
#include <hip/hip_bf16.h>

// ---- problem constants ----
#define T_TOK 2048
#define HID   1024
#define FF    1024
#define NEXP  8
#define NPAIR 4096

// ---- GEMM tiling ----
#define BM 128
#define BN 64
#define BK 32            // per sub-step; K-unroll=2 -> 64 per barrier interval
#define MAX_MT 40
#define MAXROWS (MAX_MT*BM)   // 5120
#define PPT (NPAIR/256)       // 16 pairs per setup thread

using bf16x8 = __attribute__((ext_vector_type(8))) __bf16;
using f32x4  = __attribute__((ext_vector_type(4))) float;

__device__ __forceinline__ unsigned short f2bf(float f) {
    unsigned int u = __float_as_uint(f);
    unsigned int r = (u + 0x7FFF + ((u >> 16) & 1)) >> 16;   // RNE
    return (unsigned short)r;
}

__device__ __forceinline__ void gll16(const unsigned short* g, unsigned short* l) {
    __builtin_amdgcn_global_load_lds(
        (const __attribute__((address_space(1))) void*)(const void*)g,
        (__attribute__((address_space(3))) void*)(void*)l, 16, 0, 0);
}

// ---------------- setup: bucket pairs by expert via prefix scan (no atomics) ----
__global__ void setup_kernel(const int* __restrict__ ids,
                             const float* __restrict__ tw,
                             int* __restrict__ pair_pos,
                             int* __restrict__ row_tok,
                             float* __restrict__ row_w,
                             int* __restrict__ meta) {
    __shared__ int S[2][256][NEXP];      // 16 KB ping-pong scan buffers
    __shared__ int base[NEXP];
    int tid = threadIdx.x;
    int myc[NEXP];
    int eloc[PPT];
#pragma unroll
    for (int e = 0; e < NEXP; e++) myc[e] = 0;
#pragma unroll
    for (int i = 0; i < PPT; i++) {
        int e = ids[tid * PPT + i];
        eloc[i] = e;
#pragma unroll
        for (int ee = 0; ee < NEXP; ee++) myc[ee] += (e == ee);
    }
#pragma unroll
    for (int e = 0; e < NEXP; e++) S[0][tid][e] = myc[e];
    __syncthreads();
    int src = 0;
    for (int d = 1; d < 256; d <<= 1) {
#pragma unroll
        for (int e = 0; e < NEXP; e++) {
            int v = S[src][tid][e];
            if (tid >= d) v += S[src][tid - d][e];
            S[src ^ 1][tid][e] = v;
        }
        __syncthreads();
        src ^= 1;
    }
    // S[src][tid][e] = inclusive prefix of counts
    if (tid == 0) {
        int mt = 0;
        for (int e = 0; e < NEXP; e++) {
            meta[e] = mt;
            base[e] = mt * BM;
            mt += (S[src][255][e] + BM - 1) / BM;
        }
        meta[NEXP] = mt;
    }
    for (int i = tid; i < MAXROWS; i += 256) row_tok[i] = -1;
    __syncthreads();
    int off[NEXP];
#pragma unroll
    for (int e = 0; e < NEXP; e++) off[e] = base[e] + S[src][tid][e] - myc[e];
#pragma unroll
    for (int i = 0; i < PPT; i++) {
        int p = tid * PPT + i;
        int e = eloc[i];
        int pos = 0;
#pragma unroll
        for (int ee = 0; ee < NEXP; ee++) if (e == ee) pos = off[ee]++;
        pair_pos[p] = pos;
        row_tok[pos] = p >> 1;
        row_w[pos] = tw[p];
    }
}

// ---------------- prep: flat fp32->bf16 weight cvt + token gather ----------------
__global__ void prep_kernel(const float* __restrict__ wgu,
                            const float* __restrict__ wdn,
                            const float* __restrict__ hs,
                            const int* __restrict__ pair_pos,
                            unsigned short* __restrict__ wgu_b,
                            unsigned short* __restrict__ wdn_b,
                            unsigned short* __restrict__ A) {
    long stride = (long)gridDim.x * blockDim.x;
    long t0 = (long)blockIdx.x * blockDim.x + threadIdx.x;
    const long NW1 = (long)NEXP * 2 * FF * HID / 4;
    for (long i = t0; i < NW1; i += stride) {
        float4 v = ((const float4*)wgu)[i];
        ushort4 o; o.x = f2bf(v.x); o.y = f2bf(v.y); o.z = f2bf(v.z); o.w = f2bf(v.w);
        ((ushort4*)wgu_b)[i] = o;
    }
    const long NW2 = (long)NEXP * HID * FF / 4;
    for (long i = t0; i < NW2; i += stride) {
        float4 v = ((const float4*)wdn)[i];
        ushort4 o; o.x = f2bf(v.x); o.y = f2bf(v.y); o.z = f2bf(v.z); o.w = f2bf(v.w);
        ((ushort4*)wdn_b)[i] = o;
    }
    const long NG = (long)NPAIR * HID / 4;
    for (long i = t0; i < NG; i += stride) {
        int p = (int)(i >> 8);           // HID/4 = 256 float4 per row
        int c = (int)(i & 255);
        int t = p >> 1;
        float4 v = ((const float4*)(hs + (long)t * HID))[c];
        ushort4 o; o.x = f2bf(v.x); o.y = f2bf(v.y); o.z = f2bf(v.z); o.w = f2bf(v.w);
        ((ushort4*)(A + (long)pair_pos[p] * HID))[c] = o;
    }
}

// ---------------- grouped GEMM, K-unroll=2, xor-swizzled LDS ----------------
// EPI==1: B is wgu_b [e][gate rows 0..FF-1 | up rows FF..2FF-1]; staging de-interleaves
//         so LDS col n0+rr: even rr = gate f, odd rr = up f, f=(n0+rr)>>1.
//         Epilogue: silu(gate)*up via lane-pair shuffle -> bf16 act (Ntot/2 cols).
// EPI==2: weighted atomic scatter-combine into fp32 out via row_tok/row_w.
template<int EPI>
__global__ __launch_bounds__(256)
void gemm_moe(const unsigned short* __restrict__ A,
              const unsigned short* __restrict__ B,
              unsigned short* __restrict__ Cbf,
              float* __restrict__ outf,
              const int* __restrict__ meta,
              const int* __restrict__ row_tok,
              const float* __restrict__ row_w,
              int K, int Ntot, long Bexp) {
    __shared__ unsigned short As[2][BM * BK];   // 16 KB
    __shared__ unsigned short Bs[2][BN * BK];   // 8 KB
    int bx = blockIdx.x, by = blockIdx.y;
    if (bx >= meta[NEXP]) return;
    int e = 0;
#pragma unroll
    for (int i = 1; i < NEXP; i++) if (bx >= meta[i]) e = i;

    long m0 = (long)bx * BM;
    int n0 = by * BN;
    const unsigned short* Ab = A + m0 * K;
    const unsigned short* Bb = B + (long)e * Bexp;

    int tid = threadIdx.x, lane = tid & 63, wv = tid >> 6;
    const int r = lane & 15;
    const int q = lane >> 4;
    const int mw = (wv >> 1) * 64, nw = (wv & 1) * 32;
    const int sw = (q ^ ((r >> 1) & 3)) * 8;   // swizzled k-chunk offset for frag reads

    f32x4 acc[4][2] = {};

    for (int k0 = 0; k0 < K; k0 += 2 * BK) {
        __syncthreads();
#pragma unroll
        for (int s = 0; s < 2; s++) {
#pragma unroll
            for (int it = 0; it < 2; it++) {           // A: 512 chunks per buf
                int c = it * 256 + tid;
                int row = c >> 2, cp = c & 3;
                int cc = cp ^ ((row >> 1) & 3);
                gll16(Ab + (long)row * K + (k0 + s * BK + cc * 8), &As[s][c * 8]);
            }
            {                                           // B: 256 chunks per buf
                int c = tid;
                int row = c >> 2, cp = c & 3;
                int cc = cp ^ ((row >> 1) & 3);
                long grow;
                if (EPI == 1) grow = ((row & 1) ? FF : 0) + ((n0 + row) >> 1);
                else          grow = n0 + row;
                gll16(Bb + grow * (long)K + (k0 + s * BK + cc * 8), &Bs[s][c * 8]);
            }
        }
        __syncthreads();

#pragma unroll
        for (int s = 0; s < 2; s++) {
            bf16x8 a[4], b[2];
#pragma unroll
            for (int i = 0; i < 4; i++)
                a[i] = *(const bf16x8*)&As[s][(mw + i * 16 + r) * BK + sw];
#pragma unroll
            for (int j = 0; j < 2; j++)
                b[j] = *(const bf16x8*)&Bs[s][(nw + j * 16 + r) * BK + sw];
#pragma unroll
            for (int i = 0; i < 4; i++)
#pragma unroll
                for (int j = 0; j < 2; j++)
                    acc[i][j] = __builtin_amdgcn_mfma_f32_16x16x32_bf16(a[i], b[j], acc[i][j], 0, 0, 0);
        }
    }

    // D layout: row = q*4 + reg, col = lane&15 within each 16x16 tile
    if (EPI == 1) {
#pragma unroll
        for (int i = 0; i < 4; i++) {
            long rowb = m0 + mw + i * 16 + q * 4;
#pragma unroll
            for (int j = 0; j < 2; j++) {
                int n = n0 + nw + j * 16 + r;
#pragma unroll
                for (int reg = 0; reg < 4; reg++) {
                    float v = acc[i][j][reg];
                    float o = __shfl_xor(v, 1);
                    if (!(r & 1)) {
                        float g = v, u = o;
                        float s = g / (1.f + __expf(-g)) * u;
                        Cbf[(rowb + reg) * (long)(Ntot / 2) + (n >> 1)] = f2bf(s);
                    }
                }
            }
        }
    } else {
#pragma unroll
        for (int i = 0; i < 4; i++) {
            int rowb = (int)m0 + mw + i * 16 + q * 4;
            int tk[4]; float w[4];
#pragma unroll
            for (int reg = 0; reg < 4; reg++) {
                tk[reg] = row_tok[rowb + reg];
                w[reg] = row_w[rowb + reg];
            }
#pragma unroll
            for (int j = 0; j < 2; j++) {
                int n = n0 + nw + j * 16 + r;
#pragma unroll
                for (int reg = 0; reg < 4; reg++) {
                    if (tk[reg] >= 0)
                        atomicAdd(outf + (long)tk[reg] * HID + n, w[reg] * acc[i][j][reg]);
                }
            }
        }
    }
}

extern "C" void kernel_launch(void* const* d_in, const int* in_sizes, int n_in,
                              void* d_out, int out_size, void* d_ws, size_t ws_size,
                              hipStream_t stream) {
    const float* hs  = (const float*)d_in[0];
    const float* tw  = (const float*)d_in[1];
    const int*   ids = (const int*)d_in[2];
    const float* wgu = (const float*)d_in[3];
    const float* wdn = (const float*)d_in[4];
    float* out = (float*)d_out;

    char* ws = (char*)d_ws;
    size_t off = 0;
    auto alloc = [&](size_t bytes) -> void* {
        void* p = ws + off;
        off += (bytes + 255) & ~(size_t)255;
        return p;
    };
    unsigned short* wgu_b = (unsigned short*)alloc((size_t)NEXP * 2 * FF * HID * 2); // 32 MB
    unsigned short* wdn_b = (unsigned short*)alloc((size_t)NEXP * HID * FF * 2);     // 16 MB
    unsigned short* Abuf  = (unsigned short*)alloc((size_t)MAXROWS * HID * 2);       // 10 MB
    unsigned short* act   = (unsigned short*)alloc((size_t)MAXROWS * FF * 2);        // 10 MB
    int*   pair_pos = (int*)alloc(NPAIR * 4);
    int*   row_tok  = (int*)alloc(MAXROWS * 4);
    float* row_w    = (float*)alloc(MAXROWS * 4);
    int*   meta     = (int*)alloc(64);

    // pad rows of A must be zero (partial M-tiles); out accumulated via atomics
    hipMemsetAsync(Abuf, 0, (size_t)MAXROWS * HID * 2, stream);
    hipMemsetAsync(out, 0, (size_t)T_TOK * HID * 4, stream);

    setup_kernel<<<1, 256, 0, stream>>>(ids, tw, pair_pos, row_tok, row_w, meta);
    prep_kernel<<<2048, 256, 0, stream>>>(wgu, wdn, hs, pair_pos, wgu_b, wdn_b, Abuf);

    // GEMM1: (rows x 1024) x B_e(2048 x 1024)^T -> fused silu -> act (rows x 1024)
    gemm_moe<1><<<dim3(MAX_MT, (2 * FF) / BN), 256, 0, stream>>>(
        Abuf, wgu_b, act, nullptr, meta, nullptr, nullptr,
        HID, 2 * FF, (long)(2 * FF) * HID);

    // GEMM2: (rows x 1024) x B_e(1024 x 1024)^T -> weighted atomic combine -> out
    gemm_moe<2><<<dim3(MAX_MT, HID / BN), 256, 0, stream>>>(
        act, wdn_b, nullptr, out, meta, row_tok, row_w,
        FF, HID, (long)HID * FF);
}

// Round 4
// 205.553 us; speedup vs baseline: 1.1728x; 1.1536x over previous
//
#include <hip/hip_runtime.h>
#include <hip/hip_bf16.h>

// ---- problem constants ----
#define T_TOK 2048
#define HID   1024
#define FF    1024
#define NEXP  8
#define NPAIR 4096

// ---- GEMM tiling ----
#define BM 128
#define BN 64
#define BK 32
#define MAX_MT 40
#define MAXROWS (MAX_MT*BM)   // 5120
#define PPT (NPAIR/256)       // 16

using bf16x8 = __attribute__((ext_vector_type(8))) __bf16;
using f32x4  = __attribute__((ext_vector_type(4))) float;

__device__ __forceinline__ unsigned short f2bf(float f) {
    unsigned int u = __float_as_uint(f);
    return (unsigned short)((u + 0x7FFF + ((u >> 16) & 1)) >> 16);   // RNE
}
__device__ __forceinline__ float bf2f(unsigned short s) {
    return __uint_as_float(((unsigned int)s) << 16);
}
__device__ __forceinline__ void gll16(const unsigned short* g, unsigned short* l) {
    __builtin_amdgcn_global_load_lds(
        (const __attribute__((address_space(1))) void*)(const void*)g,
        (__attribute__((address_space(3))) void*)(void*)l, 16, 0, 0);
}

// ---------------- prep (blocks 0..2047) + setup (block 2048) ----------------
__global__ void prep_kernel(const float* __restrict__ wgu,
                            const float* __restrict__ wdn,
                            const float* __restrict__ hs,
                            const int* __restrict__ ids,
                            int* __restrict__ pair_pos,
                            int* __restrict__ row_tok,
                            int* __restrict__ meta,
                            unsigned short* __restrict__ wgu_b,
                            unsigned short* __restrict__ wdn_b,
                            unsigned short* __restrict__ hs_b) {
    int tid = threadIdx.x;
    if (blockIdx.x == 2048) {
        // ---- setup: bucket pairs by expert via prefix scan (no atomics) ----
        __shared__ int S[2][256][NEXP];
        __shared__ int base[NEXP];
        int myc[NEXP];
        int eloc[PPT];
#pragma unroll
        for (int e = 0; e < NEXP; e++) myc[e] = 0;
#pragma unroll
        for (int i = 0; i < PPT; i++) {
            int e = ids[tid * PPT + i];
            eloc[i] = e;
#pragma unroll
            for (int ee = 0; ee < NEXP; ee++) myc[ee] += (e == ee);
        }
#pragma unroll
        for (int e = 0; e < NEXP; e++) S[0][tid][e] = myc[e];
        __syncthreads();
        int src = 0;
        for (int d = 1; d < 256; d <<= 1) {
#pragma unroll
            for (int e = 0; e < NEXP; e++) {
                int v = S[src][tid][e];
                if (tid >= d) v += S[src][tid - d][e];
                S[src ^ 1][tid][e] = v;
            }
            __syncthreads();
            src ^= 1;
        }
        if (tid == 0) {
            int mt = 0;
            for (int e = 0; e < NEXP; e++) {
                meta[e] = mt;
                base[e] = mt * BM;
                mt += (S[src][255][e] + BM - 1) / BM;
            }
            meta[NEXP] = mt;
        }
        for (int i = tid; i < MAXROWS; i += 256) row_tok[i] = -1;
        __syncthreads();
        int off[NEXP];
#pragma unroll
        for (int e = 0; e < NEXP; e++) off[e] = base[e] + S[src][tid][e] - myc[e];
#pragma unroll
        for (int i = 0; i < PPT; i++) {
            int p = tid * PPT + i;
            int e = eloc[i];
            int pos = 0;
#pragma unroll
            for (int ee = 0; ee < NEXP; ee++) if (e == ee) pos = off[ee]++;
            pair_pos[p] = pos;
            row_tok[pos] = p >> 1;
        }
        return;
    }
    // ---- flat fp32 -> bf16 conversions ----
    long stride = 2048L * 256;
    long t0 = (long)blockIdx.x * 256 + tid;
    const long NW1 = (long)NEXP * 2 * FF * HID / 4;
    for (long i = t0; i < NW1; i += stride) {
        float4 v = ((const float4*)wgu)[i];
        ushort4 o; o.x = f2bf(v.x); o.y = f2bf(v.y); o.z = f2bf(v.z); o.w = f2bf(v.w);
        ((ushort4*)wgu_b)[i] = o;
    }
    const long NW2 = (long)NEXP * HID * FF / 4;
    for (long i = t0; i < NW2; i += stride) {
        float4 v = ((const float4*)wdn)[i];
        ushort4 o; o.x = f2bf(v.x); o.y = f2bf(v.y); o.z = f2bf(v.z); o.w = f2bf(v.w);
        ((ushort4*)wdn_b)[i] = o;
    }
    const long NH = (long)T_TOK * HID / 4;
    for (long i = t0; i < NH; i += stride) {
        float4 v = ((const float4*)hs)[i];
        ushort4 o; o.x = f2bf(v.x); o.y = f2bf(v.y); o.z = f2bf(v.z); o.w = f2bf(v.w);
        ((ushort4*)hs_b)[i] = o;
    }
}

// ---------------- grouped GEMM, XCD-swizzled 1-D grid, prefetch dbuf ----------------
// EPI==1: A rows indirect via row_tok (clamped) into hs_b; B = wgu_b with gate/up
//         de-interleave in staging; epilogue silu(gate)*up -> bf16 act (FF cols).
// EPI==2: A = act (bucket-ordered, direct); epilogue plain bf16 store to ybuf.
template<int EPI, int NBY>
__global__ __launch_bounds__(256)
void gemm_moe(const unsigned short* __restrict__ A,
              const unsigned short* __restrict__ B,
              unsigned short* __restrict__ Cbf,
              const int* __restrict__ meta,
              const int* __restrict__ row_tok,
              int K, long Bexp) {
    __shared__ unsigned short As[2][BM * BK];   // 16 KB
    __shared__ unsigned short Bs[2][BN * BK];   // 8 KB

    // XCD-locality decode: xcd = L%8 gets NBY/8 consecutive by-slabs for ALL bx
    int L = blockIdx.x;
    int xcd = L & 7;
    int slot = L >> 3;
    constexpr int PER = NBY / 8;
    int by = xcd * PER + (slot % PER);
    int bx = slot / PER;
    if (bx >= meta[NEXP]) return;
    int e = 0;
#pragma unroll
    for (int i = 1; i < NEXP; i++) if (bx >= meta[i]) e = i;

    long m0 = (long)bx * BM;
    int n0 = by * BN;
    const unsigned short* Bb = B + (long)e * Bexp;

    int tid = threadIdx.x, lane = tid & 63, wv = tid >> 6;
    const int r = lane & 15;
    const int q = lane >> 4;
    const int mw = (wv >> 1) * 64, nw = (wv & 1) * 32;
    const int sw = (q ^ ((r >> 1) & 3)) * 8;

    // per-thread staging pointers (rows fixed across K)
    const unsigned short* ap[2];
#pragma unroll
    for (int h = 0; h < 2; h++) {
        int c = h * 256 + tid;
        int row = c >> 2, cp = c & 3;
        int cc = cp ^ ((row >> 1) & 3);
        long grow;
        if (EPI == 1) {
            int tk = row_tok[m0 + row];
            if (tk < 0) tk = 0;               // pad rows: finite garbage, never read
            grow = tk;
        } else {
            grow = m0 + row;
        }
        ap[h] = A + grow * (long)K + cc * 8;
    }
    const unsigned short* bp;
    {
        int c = tid;
        int row = c >> 2, cp = c & 3;
        int cc = cp ^ ((row >> 1) & 3);
        long grow;
        if (EPI == 1) grow = ((row & 1) ? FF : 0) + ((n0 + row) >> 1);
        else          grow = n0 + row;
        bp = Bb + grow * (long)K + cc * 8;
    }

    auto stage = [&](int s, int k0) {
#pragma unroll
        for (int h = 0; h < 2; h++)
            gll16(ap[h] + k0, &As[s][(h * 256 + tid) * 8]);
        gll16(bp + k0, &Bs[s][tid * 8]);
    };

    f32x4 acc[4][2] = {};
    const int NKI = K / BK;   // 32
    stage(0, 0);
    for (int ki = 0; ki < NKI; ki++) {
        __syncthreads();      // buf[ki&1] loads landed; buf[(ki+1)&1] free to overwrite
        if (ki + 1 < NKI) stage((ki + 1) & 1, (ki + 1) * BK);
        int s = ki & 1;
        bf16x8 a[4], b[2];
#pragma unroll
        for (int i = 0; i < 4; i++)
            a[i] = *(const bf16x8*)&As[s][(mw + i * 16 + r) * BK + sw];
#pragma unroll
        for (int j = 0; j < 2; j++)
            b[j] = *(const bf16x8*)&Bs[s][(nw + j * 16 + r) * BK + sw];
#pragma unroll
        for (int i = 0; i < 4; i++)
#pragma unroll
            for (int j = 0; j < 2; j++)
                acc[i][j] = __builtin_amdgcn_mfma_f32_16x16x32_bf16(a[i], b[j], acc[i][j], 0, 0, 0);
        __syncthreads();      // all reads of buf[s] done before next overwrite cycle
    }

    // D layout: row = q*4 + reg, col = lane&15 within each 16x16 tile
    if (EPI == 1) {
#pragma unroll
        for (int i = 0; i < 4; i++) {
            long rowb = m0 + mw + i * 16 + q * 4;
#pragma unroll
            for (int j = 0; j < 2; j++) {
                int n = n0 + nw + j * 16 + r;
#pragma unroll
                for (int reg = 0; reg < 4; reg++) {
                    float v = acc[i][j][reg];
                    float o = __shfl_xor(v, 1);
                    if (!(r & 1)) {
                        float g = v, u = o;
                        float s2 = g / (1.f + __expf(-g)) * u;
                        Cbf[(rowb + reg) * (long)FF + (n >> 1)] = f2bf(s2);
                    }
                }
            }
        }
    } else {
#pragma unroll
        for (int i = 0; i < 4; i++) {
            long rowb = m0 + mw + i * 16 + q * 4;
#pragma unroll
            for (int j = 0; j < 2; j++) {
                int n = n0 + nw + j * 16 + r;
#pragma unroll
                for (int reg = 0; reg < 4; reg++)
                    Cbf[(rowb + reg) * (long)HID + n] = f2bf(acc[i][j][reg]);
            }
        }
    }
}

// ---------------- weighted combine ----------------
__global__ void combine_kernel(const unsigned short* __restrict__ y,
                               const float* __restrict__ tw,
                               const int* __restrict__ pair_pos,
                               float* __restrict__ out) {
    int t = blockIdx.x;
    int c = threadIdx.x * 4;
    int p0 = pair_pos[t * 2], p1 = pair_pos[t * 2 + 1];
    float w0 = tw[t * 2], w1 = tw[t * 2 + 1];
    ushort4 a = *(const ushort4*)(y + (long)p0 * HID + c);
    ushort4 b = *(const ushort4*)(y + (long)p1 * HID + c);
    float4 o;
    o.x = w0 * bf2f(a.x) + w1 * bf2f(b.x);
    o.y = w0 * bf2f(a.y) + w1 * bf2f(b.y);
    o.z = w0 * bf2f(a.z) + w1 * bf2f(b.z);
    o.w = w0 * bf2f(a.w) + w1 * bf2f(b.w);
    *(float4*)(out + (long)t * HID + c) = o;
}

extern "C" void kernel_launch(void* const* d_in, const int* in_sizes, int n_in,
                              void* d_out, int out_size, void* d_ws, size_t ws_size,
                              hipStream_t stream) {
    const float* hs  = (const float*)d_in[0];
    const float* tw  = (const float*)d_in[1];
    const int*   ids = (const int*)d_in[2];
    const float* wgu = (const float*)d_in[3];
    const float* wdn = (const float*)d_in[4];
    float* out = (float*)d_out;

    char* ws = (char*)d_ws;
    size_t off = 0;
    auto alloc = [&](size_t bytes) -> void* {
        void* p = ws + off;
        off += (bytes + 255) & ~(size_t)255;
        return p;
    };
    unsigned short* wgu_b = (unsigned short*)alloc((size_t)NEXP * 2 * FF * HID * 2); // 32 MB
    unsigned short* wdn_b = (unsigned short*)alloc((size_t)NEXP * HID * FF * 2);     // 16 MB
    unsigned short* hs_b  = (unsigned short*)alloc((size_t)T_TOK * HID * 2);         // 4 MB
    unsigned short* act   = (unsigned short*)alloc((size_t)MAXROWS * FF * 2);        // 10 MB
    unsigned short* ybuf  = (unsigned short*)alloc((size_t)MAXROWS * HID * 2);       // 10 MB
    int* pair_pos = (int*)alloc(NPAIR * 4);
    int* row_tok  = (int*)alloc(MAXROWS * 4);
    int* meta     = (int*)alloc(64);

    prep_kernel<<<2049, 256, 0, stream>>>(wgu, wdn, hs, ids,
                                          pair_pos, row_tok, meta,
                                          wgu_b, wdn_b, hs_b);

    // GEMM1: (rows x 1024) x B_e(2048 x 1024)^T -> fused silu -> act (rows x 1024)
    gemm_moe<1, 32><<<32 * MAX_MT, 256, 0, stream>>>(
        hs_b, wgu_b, act, meta, row_tok, HID, (long)(2 * FF) * HID);

    // GEMM2: (rows x 1024) x B_e(1024 x 1024)^T -> ybuf (rows x 1024) bf16
    gemm_moe<2, 16><<<16 * MAX_MT, 256, 0, stream>>>(
        act, wdn_b, ybuf, meta, row_tok, FF, (long)HID * FF);

    combine_kernel<<<T_TOK, 256, 0, stream>>>(ybuf, tw, pair_pos, out);
}